// Round 1
// baseline (2744.742 us; speedup 1.0000x reference)
//
#include <hip/hip_runtime.h>
#include <hip/hip_bf16.h>

#define NROW_F 8192
#define NROW_B 65536
#define KDIM   384
#define KSTEPS 12              // 384 / 32
#define NCHUNK 16
#define CHUNK_ROWS (NROW_B / NCHUNK)   // 4096
#define CHUNK_TILES (CHUNK_ROWS / 16)  // 256

typedef __bf16 bf16x8 __attribute__((ext_vector_type(8)));
typedef short  short8 __attribute__((ext_vector_type(8)));
typedef float  f32x4  __attribute__((ext_vector_type(4)));

static __device__ __forceinline__ unsigned short f2bf(float f) {
  unsigned u = __builtin_bit_cast(unsigned, f);
  u += 0x7FFFu + ((u >> 16) & 1u);
  return (unsigned short)(u >> 16);
}

static __device__ __forceinline__ bf16x8 load_bf8(const unsigned short* p) {
  short8 s = *reinterpret_cast<const short8*>(p);
  return __builtin_bit_cast(bf16x8, s);
}

// ---------------------------------------------------------------------------
// 1) L2-normalize rows (384 wide), write bf16. One wave per row.
// ---------------------------------------------------------------------------
__global__ __launch_bounds__(256) void normalize_rows_kernel(
    const float* __restrict__ in, unsigned short* __restrict__ out, int nrows) {
  int row  = blockIdx.x * 4 + (threadIdx.x >> 6);
  int lane = threadIdx.x & 63;
  if (row >= nrows) return;
  const float* r = in + (size_t)row * KDIM;
  float v[6];
  float ss = 0.f;
#pragma unroll
  for (int i = 0; i < 6; ++i) { v[i] = r[lane + i * 64]; ss += v[i] * v[i]; }
#pragma unroll
  for (int d = 1; d < 64; d <<= 1) ss += __shfl_xor(ss, d, 64);
  float inv = rsqrtf(fmaxf(ss, 1e-24f));
  unsigned short* o = out + (size_t)row * KDIM;
#pragma unroll
  for (int i = 0; i < 6; ++i) o[lane + i * 64] = f2bf(v[i] * inv);
}

// ---------------------------------------------------------------------------
// 2) max over bank rows of dot(f, mb) — MFMA 16x16x32 bf16, NT layout.
//    Block: 4 waves x 16 feature rows = 64 rows. Grid: (128 ftile, 16 chunk).
//    partial[chunk][row] = max sim over that chunk's 4096 bank rows.
// ---------------------------------------------------------------------------
__global__ __launch_bounds__(256) void maxsim_kernel(
    const unsigned short* __restrict__ F,   // 8192 x 384 bf16
    const unsigned short* __restrict__ MB,  // 65536 x 384 bf16
    float* __restrict__ partial) {          // NCHUNK x 8192
  const int wave  = threadIdx.x >> 6;
  const int lane  = threadIdx.x & 63;
  const int l15   = lane & 15;
  const int lhi   = lane >> 4;                         // 0..3
  const int frow0 = blockIdx.x * 64 + wave * 16;       // this wave's 16 rows
  const int chunk = blockIdx.y;

  // A fragments: row = frow0 + l15, k = ks*32 + lhi*8 + j  (hoisted, reused)
  const unsigned short* Fp = F + (size_t)(frow0 + l15) * KDIM + lhi * 8;
  bf16x8 a[KSTEPS];
#pragma unroll
  for (int ks = 0; ks < KSTEPS; ++ks) a[ks] = load_bf8(Fp + ks * 32);

  f32x4 vmax = {-1e30f, -1e30f, -1e30f, -1e30f};
  const unsigned short* Bp =
      MB + (size_t)(chunk * CHUNK_ROWS + l15) * KDIM + lhi * 8;

  for (int t = 0; t < CHUNK_TILES; ++t) {
    f32x4 acc = {0.f, 0.f, 0.f, 0.f};
#pragma unroll
    for (int ks = 0; ks < KSTEPS; ++ks) {
      bf16x8 b = load_bf8(Bp + ks * 32);
      acc = __builtin_amdgcn_mfma_f32_16x16x32_bf16(a[ks], b, acc, 0, 0, 0);
    }
#pragma unroll
    for (int j = 0; j < 4; ++j) vmax[j] = fmaxf(vmax[j], acc[j]);
    Bp += 16 * KDIM;
  }

  // C/D layout: col(=bank idx) = lane&15, row(=feature idx) = (lane>>4)*4 + j.
  // Reduce max over the 16 col slots (lanes sharing lane>>4).
#pragma unroll
  for (int d = 1; d < 16; d <<= 1) {
#pragma unroll
    for (int j = 0; j < 4; ++j)
      vmax[j] = fmaxf(vmax[j], __shfl_xor(vmax[j], d, 64));
  }
  if (l15 == 0) {
    int row = frow0 + lhi * 4;
#pragma unroll
    for (int j = 0; j < 4; ++j)
      partial[chunk * NROW_F + row + j] = vmax[j];
  }
}

// ---------------------------------------------------------------------------
// 3) combine partial maxes -> min_dists = clip(1 - max, 0, 2)
// ---------------------------------------------------------------------------
__global__ __launch_bounds__(256) void combine_kernel(
    const float* __restrict__ partial, float* __restrict__ md) {
  int r = blockIdx.x * 256 + threadIdx.x;
  if (r >= NROW_F) return;
  float m = -1e30f;
#pragma unroll
  for (int c = 0; c < NCHUNK; ++c) m = fmaxf(m, partial[c * NROW_F + r]);
  float d = 1.0f - m;
  d = fminf(fmaxf(d, 0.0f), 2.0f);
  md[r] = d;
}

// ---------------------------------------------------------------------------
// 4) per-batch top-10 mean -> pred_score
// ---------------------------------------------------------------------------
__global__ __launch_bounds__(256) void topk_kernel(
    const float* __restrict__ md, float* __restrict__ out) {
  __shared__ float buf[1024];
  __shared__ float svals[256];
  __shared__ int   sidx[256];
  int b = blockIdx.x, tid = threadIdx.x;
  for (int i = tid; i < 1024; i += 256) buf[i] = md[b * 1024 + i];
  __syncthreads();
  float total = 0.f;
  for (int it = 0; it < 10; ++it) {
    float best = -1e30f; int bi = 0;
    for (int i = tid; i < 1024; i += 256)
      if (buf[i] > best) { best = buf[i]; bi = i; }
    svals[tid] = best; sidx[tid] = bi;
    __syncthreads();
    for (int s = 128; s > 0; s >>= 1) {
      if (tid < s && svals[tid + s] > svals[tid]) {
        svals[tid] = svals[tid + s]; sidx[tid] = sidx[tid + s];
      }
      __syncthreads();
    }
    if (tid == 0) { total += svals[0]; buf[sidx[0]] = -1e30f; }
    __syncthreads();
  }
  if (tid == 0) out[b] = total * 0.1f;
}

// ---------------------------------------------------------------------------
// 5) W = blur_1d ∘ bilinear_resize_1d : 448 x 32 operator (both axes equal).
//    Bilinear: half-pixel centers, clamp at edges (== jax normalized weights).
//    Blur: sigma=4, radius=16, reflect padding.
// ---------------------------------------------------------------------------
__global__ __launch_bounds__(256) void build_w_kernel(float* __restrict__ W) {
  int idx = blockIdx.x * 256 + threadIdx.x;
  if (idx >= 448 * 32) return;
  int y = idx >> 5, g = idx & 31;
  float ksum = 0.f, acc = 0.f;
#pragma unroll
  for (int t = -16; t <= 16; ++t) {
    float ft = (float)t * 0.25f;
    float kv = expf(-0.5f * ft * ft);
    ksum += kv;
    int p = y + t;
    p = (p < 0) ? -p : ((p > 447) ? 894 - p : p);
    float src = ((float)p + 0.5f) * (1.0f / 14.0f) - 0.5f;
    float fl = floorf(src);
    int i0 = (int)fl;
    float fr = src - fl;
    int c0 = i0 < 0 ? 0 : (i0 > 31 ? 31 : i0);
    int i1 = i0 + 1;
    int c1 = i1 < 0 ? 0 : (i1 > 31 ? 31 : i1);
    float w = 0.f;
    if (c0 == g) w += 1.0f - fr;
    if (c1 == g) w += fr;
    acc += kv * w;
  }
  W[idx] = acc / ksum;
}

// ---------------------------------------------------------------------------
// 6) anomaly_map = W · md_grid · W^T   (two small stages)
// ---------------------------------------------------------------------------
__global__ __launch_bounds__(256) void map_stage1_kernel(
    const float* __restrict__ md, const float* __restrict__ W,
    float* __restrict__ tmp) {  // 8 x 448 x 32
  int idx = blockIdx.x * 256 + threadIdx.x;
  if (idx >= 8 * 448 * 32) return;
  int gx = idx & 31;
  int y  = (idx >> 5) % 448;
  int b  = idx / (448 * 32);
  const float* w = W + y * 32;
  const float* m = md + b * 1024 + gx;
  float s = 0.f;
#pragma unroll
  for (int gy = 0; gy < 32; ++gy) s += w[gy] * m[gy * 32];
  tmp[idx] = s;
}

__global__ __launch_bounds__(256) void map_stage2_kernel(
    const float* __restrict__ tmp, const float* __restrict__ W,
    float* __restrict__ out) {  // 8 x 448 x 448
  int idx = blockIdx.x * 256 + threadIdx.x;
  if (idx >= 8 * 448 * 448) return;
  int x    = idx % 448;
  int ypos = idx / 448;  // b*448 + y
  const float* w = W + x * 32;
  const float* t = tmp + ypos * 32;
  float s = 0.f;
#pragma unroll
  for (int gx = 0; gx < 32; ++gx) s += w[gx] * t[gx];
  out[idx] = s;
}

// ---------------------------------------------------------------------------
extern "C" void kernel_launch(void* const* d_in, const int* in_sizes, int n_in,
                              void* d_out, int out_size, void* d_ws, size_t ws_size,
                              hipStream_t stream) {
  const float* features = (const float*)d_in[0];   // 8*1024*384
  const float* bank     = (const float*)d_in[1];   // 65536*384
  float* out = (float*)d_out;                      // [8 scores][8*448*448 map]

  char* ws = (char*)d_ws;
  unsigned short* mbh = (unsigned short*)ws;                    // 50,331,648 B
  unsigned short* fh  = (unsigned short*)(ws + 50331648);       //  6,291,456 B
  float* partial      = (float*)(ws + 56623104);                //    524,288 B
  float* md           = (float*)(ws + 57147392);                //     32,768 B
  float* W            = (float*)(ws + 57180160);                //     57,344 B
  float* tmp          = (float*)(ws + 57237504);                //    458,752 B

  normalize_rows_kernel<<<NROW_B / 4, 256, 0, stream>>>(bank, mbh, NROW_B);
  normalize_rows_kernel<<<NROW_F / 4, 256, 0, stream>>>(features, fh, NROW_F);
  maxsim_kernel<<<dim3(NROW_F / 64, NCHUNK), 256, 0, stream>>>(fh, mbh, partial);
  combine_kernel<<<NROW_F / 256, 256, 0, stream>>>(partial, md);
  topk_kernel<<<8, 256, 0, stream>>>(md, out);
  build_w_kernel<<<(448 * 32 + 255) / 256, 256, 0, stream>>>(W);
  map_stage1_kernel<<<(8 * 448 * 32 + 255) / 256, 256, 0, stream>>>(md, W, tmp);
  map_stage2_kernel<<<(8 * 448 * 448 + 255) / 256, 256, 0, stream>>>(tmp, W, out + 8);
}

// Round 2
// 617.026 us; speedup vs baseline: 4.4483x; 4.4483x over previous
//
#include <hip/hip_runtime.h>
#include <hip/hip_bf16.h>

#define NROW_F 8192
#define NROW_B 65536
#define KDIM   384
#define BM 128
#define BN 128
#define BK 32                  // bf16 elems; 64 bytes per row
#define NKT (KDIM / BK)        // 12
#define NSUB 8                 // N-subtiles per block (vmax carried)
#define NGRP (NROW_B / (BN * NSUB))   // 64
#define NBM  (NROW_F / BM)            // 64

typedef __bf16 bf16x8 __attribute__((ext_vector_type(8)));
typedef short  short8 __attribute__((ext_vector_type(8)));
typedef float  f32x4  __attribute__((ext_vector_type(4)));

static __device__ __forceinline__ unsigned short f2bf(float f) {
  unsigned u = __builtin_bit_cast(unsigned, f);
  u += 0x7FFFu + ((u >> 16) & 1u);
  return (unsigned short)(u >> 16);
}

static __device__ __forceinline__ bf16x8 load_bf8(const unsigned short* p) {
  short8 s = *reinterpret_cast<const short8*>(p);
  return __builtin_bit_cast(bf16x8, s);
}

static __device__ __forceinline__ void stage16(const void* g, void* l) {
  __builtin_amdgcn_global_load_lds(
      (const __attribute__((address_space(1))) unsigned int*)g,
      (__attribute__((address_space(3))) unsigned int*)l, 16, 0, 0);
}

// ---------------------------------------------------------------------------
// 1) L2-normalize rows (384 wide), write bf16. One wave per row.
// ---------------------------------------------------------------------------
__global__ __launch_bounds__(256) void normalize_rows_kernel(
    const float* __restrict__ in, unsigned short* __restrict__ out, int nrows) {
  int row  = blockIdx.x * 4 + (threadIdx.x >> 6);
  int lane = threadIdx.x & 63;
  if (row >= nrows) return;
  const float* r = in + (size_t)row * KDIM;
  float v[6];
  float ss = 0.f;
#pragma unroll
  for (int i = 0; i < 6; ++i) { v[i] = r[lane + i * 64]; ss += v[i] * v[i]; }
#pragma unroll
  for (int d = 1; d < 64; d <<= 1) ss += __shfl_xor(ss, d, 64);
  float inv = rsqrtf(fmaxf(ss, 1e-24f));
  unsigned short* o = out + (size_t)row * KDIM;
#pragma unroll
  for (int i = 0; i < 6; ++i) o[lane + i * 64] = f2bf(v[i] * inv);
}

// ---------------------------------------------------------------------------
// 2) maxsim: 128x128 MFMA tile, global_load_lds staging (m97 structure),
//    max-reduce epilogue. Block = 4 waves (2x2), wave = 64x64 out.
//    Each block: rows [bm*128, +128), cols [bgrp*1024, +1024) in 8 subtiles.
// ---------------------------------------------------------------------------
__global__ __launch_bounds__(256) void maxsim_kernel(
    const unsigned short* __restrict__ F,   // 8192 x 384 bf16
    const unsigned short* __restrict__ MB,  // 65536 x 384 bf16
    float* __restrict__ partial) {          // NGRP x 8192 (row max-sim)
  __shared__ __align__(16) unsigned short As[BM * BK];  // [row][32], 64B/row
  __shared__ __align__(16) unsigned short Bs[BN * BK];
  __shared__ float red[2][BM];

  const int tid  = threadIdx.x;
  const int wave = tid >> 6;
  const int lane = tid & 63;
  const int l15  = lane & 15;
  const int lhi  = lane >> 4;
  const int wr   = wave >> 1, wc = wave & 1;
  const int brow = blockIdx.x * BM;
  const int bgrp = blockIdx.y;

  // staging geometry: wave w covers 32 rows (2 issues x 16 rows x 64B = 1KB)
  const int   srow = wave * 32 + (lane >> 2);        // issue 0 row
  const int   scol = (lane & 3) * 16;                // byte col within 64B row
  const size_t rsB = (size_t)KDIM * 2;               // 768 B row stride

  const char* gA = (const char*)F + (size_t)(brow + srow) * rsB + scol;
  unsigned short* lA0 = &As[wave * 1024];            // elems (2048 B / wave)
  unsigned short* lB0 = &Bs[wave * 1024];

  f32x4 vm[4];
#pragma unroll
  for (int m = 0; m < 4; ++m) vm[m] = f32x4{-1e30f, -1e30f, -1e30f, -1e30f};

  for (int sb = 0; sb < NSUB; ++sb) {
    const int bcol = (bgrp * NSUB + sb) * BN;
    const char* gB = (const char*)MB + (size_t)(bcol + srow) * rsB + scol;

    f32x4 acc[4][4];
#pragma unroll
    for (int m = 0; m < 4; ++m)
#pragma unroll
      for (int n = 0; n < 4; ++n) acc[m][n] = f32x4{0.f, 0.f, 0.f, 0.f};

    for (int kt = 0; kt < NKT; ++kt) {
      const char* ga = gA + kt * (BK * 2);
      const char* gb = gB + kt * (BK * 2);
      stage16(ga,            lA0);
      stage16(ga + 16 * rsB, lA0 + 512);
      stage16(gb,            lB0);
      stage16(gb + 16 * rsB, lB0 + 512);
      __syncthreads();   // compiler drains vmcnt before barrier

      bf16x8 a[4], b[4];
#pragma unroll
      for (int m = 0; m < 4; ++m)
        a[m] = load_bf8(&As[(wr * 64 + m * 16 + l15) * BK + lhi * 8]);
#pragma unroll
      for (int n = 0; n < 4; ++n)
        b[n] = load_bf8(&Bs[(wc * 64 + n * 16 + l15) * BK + lhi * 8]);
#pragma unroll
      for (int m = 0; m < 4; ++m)
#pragma unroll
        for (int n = 0; n < 4; ++n)
          acc[m][n] = __builtin_amdgcn_mfma_f32_16x16x32_bf16(
              a[m], b[n], acc[m][n], 0, 0, 0);
      __syncthreads();   // LDS reusable for next stage
    }

    // fold this subtile's 64 cols into running row-max
#pragma unroll
    for (int m = 0; m < 4; ++m) {
      f32x4 t = acc[m][0];
#pragma unroll
      for (int n = 1; n < 4; ++n)
#pragma unroll
        for (int j = 0; j < 4; ++j) t[j] = fmaxf(t[j], acc[m][n][j]);
#pragma unroll
      for (int j = 0; j < 4; ++j) vm[m][j] = fmaxf(vm[m][j], t[j]);
    }
  }

  // reduce over the 16 col-lanes (l15)
#pragma unroll
  for (int d = 1; d < 16; d <<= 1)
#pragma unroll
    for (int m = 0; m < 4; ++m)
#pragma unroll
      for (int j = 0; j < 4; ++j)
        vm[m][j] = fmaxf(vm[m][j], __shfl_xor(vm[m][j], d, 64));

  if (l15 == 0) {
#pragma unroll
    for (int m = 0; m < 4; ++m)
#pragma unroll
      for (int j = 0; j < 4; ++j)
        red[wc][wr * 64 + m * 16 + lhi * 4 + j] = vm[m][j];
  }
  __syncthreads();
  if (tid < BM)
    partial[(size_t)bgrp * NROW_F + brow + tid] = fmax(red[0][tid], red[1][tid]);
}

// ---------------------------------------------------------------------------
// 3) combine partial maxes -> min_dists = clip(1 - max, 0, 2)
// ---------------------------------------------------------------------------
__global__ __launch_bounds__(256) void combine_kernel(
    const float* __restrict__ partial, float* __restrict__ md) {
  int r = blockIdx.x * 256 + threadIdx.x;
  if (r >= NROW_F) return;
  float m = -1e30f;
#pragma unroll
  for (int c = 0; c < NGRP; ++c) m = fmaxf(m, partial[(size_t)c * NROW_F + r]);
  float d = 1.0f - m;
  d = fminf(fmaxf(d, 0.0f), 2.0f);
  md[r] = d;
}

// ---------------------------------------------------------------------------
// 4) per-batch top-10 mean -> pred_score
// ---------------------------------------------------------------------------
__global__ __launch_bounds__(256) void topk_kernel(
    const float* __restrict__ md, float* __restrict__ out) {
  __shared__ float buf[1024];
  __shared__ float svals[256];
  __shared__ int   sidx[256];
  int b = blockIdx.x, tid = threadIdx.x;
  for (int i = tid; i < 1024; i += 256) buf[i] = md[b * 1024 + i];
  __syncthreads();
  float total = 0.f;
  for (int it = 0; it < 10; ++it) {
    float best = -1e30f; int bi = 0;
    for (int i = tid; i < 1024; i += 256)
      if (buf[i] > best) { best = buf[i]; bi = i; }
    svals[tid] = best; sidx[tid] = bi;
    __syncthreads();
    for (int s = 128; s > 0; s >>= 1) {
      if (tid < s && svals[tid + s] > svals[tid]) {
        svals[tid] = svals[tid + s]; sidx[tid] = sidx[tid + s];
      }
      __syncthreads();
    }
    if (tid == 0) { total += svals[0]; buf[sidx[0]] = -1e30f; }
    __syncthreads();
  }
  if (tid == 0) out[b] = total * 0.1f;
}

// ---------------------------------------------------------------------------
// 5) W = blur_1d ∘ bilinear_resize_1d : 448 x 32 operator.
// ---------------------------------------------------------------------------
__global__ __launch_bounds__(256) void build_w_kernel(float* __restrict__ W) {
  int idx = blockIdx.x * 256 + threadIdx.x;
  if (idx >= 448 * 32) return;
  int y = idx >> 5, g = idx & 31;
  float ksum = 0.f, acc = 0.f;
#pragma unroll
  for (int t = -16; t <= 16; ++t) {
    float ft = (float)t * 0.25f;
    float kv = expf(-0.5f * ft * ft);
    ksum += kv;
    int p = y + t;
    p = (p < 0) ? -p : ((p > 447) ? 894 - p : p);
    float src = ((float)p + 0.5f) * (1.0f / 14.0f) - 0.5f;
    float fl = floorf(src);
    int i0 = (int)fl;
    float fr = src - fl;
    int c0 = i0 < 0 ? 0 : (i0 > 31 ? 31 : i0);
    int i1 = i0 + 1;
    int c1 = i1 < 0 ? 0 : (i1 > 31 ? 31 : i1);
    float w = 0.f;
    if (c0 == g) w += 1.0f - fr;
    if (c1 == g) w += fr;
    acc += kv * w;
  }
  W[idx] = acc / ksum;
}

// ---------------------------------------------------------------------------
// 6) anomaly_map = W · md_grid · W^T
// ---------------------------------------------------------------------------
__global__ __launch_bounds__(256) void map_stage1_kernel(
    const float* __restrict__ md, const float* __restrict__ W,
    float* __restrict__ tmp) {  // 8 x 448 x 32
  int idx = blockIdx.x * 256 + threadIdx.x;
  if (idx >= 8 * 448 * 32) return;
  int gx = idx & 31;
  int y  = (idx >> 5) % 448;
  int b  = idx / (448 * 32);
  const float* w = W + y * 32;
  const float* m = md + b * 1024 + gx;
  float s = 0.f;
#pragma unroll
  for (int gy = 0; gy < 32; ++gy) s += w[gy] * m[gy * 32];
  tmp[idx] = s;
}

__global__ __launch_bounds__(256) void map_stage2_kernel(
    const float* __restrict__ tmp, const float* __restrict__ W,
    float* __restrict__ out) {  // 8 x 448 x 448
  int idx = blockIdx.x * 256 + threadIdx.x;
  if (idx >= 8 * 448 * 448) return;
  int x    = idx % 448;
  int ypos = idx / 448;  // b*448 + y
  const float* w = W + x * 32;
  const float* t = tmp + ypos * 32;
  float s = 0.f;
#pragma unroll
  for (int gx = 0; gx < 32; ++gx) s += w[gx] * t[gx];
  out[idx] = s;
}

// ---------------------------------------------------------------------------
extern "C" void kernel_launch(void* const* d_in, const int* in_sizes, int n_in,
                              void* d_out, int out_size, void* d_ws, size_t ws_size,
                              hipStream_t stream) {
  const float* features = (const float*)d_in[0];   // 8*1024*384
  const float* bank     = (const float*)d_in[1];   // 65536*384
  float* out = (float*)d_out;                      // [8 scores][8*448*448 map]

  char* ws = (char*)d_ws;
  unsigned short* mbh = (unsigned short*)ws;                    // 50,331,648 B
  unsigned short* fh  = (unsigned short*)(ws + 50331648);       //  6,291,456 B
  float* partial      = (float*)(ws + 56623104);                //  2,097,152 B
  float* md           = (float*)(ws + 58720256);                //     32,768 B
  float* W            = (float*)(ws + 58753024);                //     57,344 B
  float* tmp          = (float*)(ws + 58810368);                //    458,752 B

  normalize_rows_kernel<<<NROW_B / 4, 256, 0, stream>>>(bank, mbh, NROW_B);
  normalize_rows_kernel<<<NROW_F / 4, 256, 0, stream>>>(features, fh, NROW_F);
  maxsim_kernel<<<dim3(NBM, NGRP), 256, 0, stream>>>(fh, mbh, partial);
  combine_kernel<<<NROW_F / 256, 256, 0, stream>>>(partial, md);
  topk_kernel<<<8, 256, 0, stream>>>(md, out);
  build_w_kernel<<<(448 * 32 + 255) / 256, 256, 0, stream>>>(W);
  map_stage1_kernel<<<(8 * 448 * 32 + 255) / 256, 256, 0, stream>>>(md, W, tmp);
  map_stage2_kernel<<<(8 * 448 * 448 + 255) / 256, 256, 0, stream>>>(tmp, W, out + 8);
}

// Round 3
// 422.359 us; speedup vs baseline: 6.4986x; 1.4609x over previous
//
#include <hip/hip_runtime.h>
#include <hip/hip_bf16.h>

#define NROW_F 8192
#define NROW_B 65536
#define KDIM   384
#define BM 256
#define BN 256
#define BK 64
#define NSUB 8
#define KT_PER_SUB 6                     // 384/64
#define NKT_TOT (NSUB * KT_PER_SUB)      // 48
#define NITER (NKT_TOT / 2)              // 24
#define NGRP (NROW_B / (BN * NSUB))      // 32
#define NBM  (NROW_F / BM)               // 32
#define NWG  (NBM * NGRP)                // 1024

#define LDS_A(b) ((b) * 32768)
#define LDS_B(b) (65536 + (b) * 32768)
#define LDS_RED  131072
#define LDS_TOTAL 135168

typedef __bf16 bf16x8 __attribute__((ext_vector_type(8)));
typedef short  short8 __attribute__((ext_vector_type(8)));
typedef float  f32x4  __attribute__((ext_vector_type(4)));

static __device__ __forceinline__ unsigned short f2bf(float f) {
  unsigned u = __builtin_bit_cast(unsigned, f);
  u += 0x7FFFu + ((u >> 16) & 1u);
  return (unsigned short)(u >> 16);
}

static __device__ __forceinline__ bf16x8 load_bf8(const void* p) {
  short8 s = *reinterpret_cast<const short8*>(p);
  return __builtin_bit_cast(bf16x8, s);
}

static __device__ __forceinline__ void stage16(const void* g, void* l) {
  __builtin_amdgcn_global_load_lds(
      (const __attribute__((address_space(1))) unsigned int*)g,
      (__attribute__((address_space(3))) unsigned int*)l, 16, 0, 0);
}

// ---------------------------------------------------------------------------
// 1) L2-normalize rows (384 wide), write bf16. One wave per row.
// ---------------------------------------------------------------------------
__global__ __launch_bounds__(256) void normalize_rows_kernel(
    const float* __restrict__ in, unsigned short* __restrict__ out, int nrows) {
  int row  = blockIdx.x * 4 + (threadIdx.x >> 6);
  int lane = threadIdx.x & 63;
  if (row >= nrows) return;
  const float* r = in + (size_t)row * KDIM;
  float v[6];
  float ss = 0.f;
#pragma unroll
  for (int i = 0; i < 6; ++i) { v[i] = r[lane + i * 64]; ss += v[i] * v[i]; }
#pragma unroll
  for (int d = 1; d < 64; d <<= 1) ss += __shfl_xor(ss, d, 64);
  float inv = rsqrtf(fmaxf(ss, 1e-24f));
  unsigned short* o = out + (size_t)row * KDIM;
#pragma unroll
  for (int i = 0; i < 6; ++i) o[lane + i * 64] = f2bf(v[i] * inv);
}

// ---------------------------------------------------------------------------
// 2) maxsim: 256x256 8-phase pipelined MFMA tile (m201 template) with
//    row-max reduction epilogue. 8 waves (2M x 4N), wave out = 128x64.
//    Block sweeps NSUB=8 col-subtiles (K=384 = 6 K-tiles each) continuously.
// ---------------------------------------------------------------------------
__global__ __launch_bounds__(512) void maxsim_kernel(
    const unsigned short* __restrict__ F,   // 8192 x 384 bf16
    const unsigned short* __restrict__ MB,  // 65536 x 384 bf16
    float* __restrict__ partial) {          // NGRP x 8192
  __shared__ __align__(16) char smem[LDS_TOTAL];

  const int tid  = threadIdx.x;
  const int wv   = tid >> 6;
  const int lane = tid & 63;
  const int l15  = lane & 15;
  const int lhi  = lane >> 4;
  const int wr   = wv >> 2;          // 0..1
  const int wc   = wv & 3;           // 0..3

  // XCD-bijective swizzle (NWG % 8 == 0)
  const int wg  = (blockIdx.x & 7) * (NWG / 8) + (blockIdx.x >> 3);
  const int bm  = wg & (NBM - 1);
  const int grp = wg >> 5;
  const size_t brow = (size_t)bm * BM;

  // ---- staging geometry (per lane, constant) ----
  // half-tile = 128 rows x 128 B; round j covers 64 rows; wave covers 8 rows.
  const int srow   = wv * 8 + (lane >> 3);
  const int gchunk = (lane & 7) ^ (((lane >> 5) & 1) << 1);  // inverse swizzle
  const int lds_off = wv * 1024;       // + lane*16 added by HW

  const char* gA0 = (const char*)F  + ((size_t)(brow + srow)) * 768 + gchunk * 16;
  const char* gB0 = (const char*)MB + ((size_t)grp * NSUB * 256 + srow) * 768 + gchunk * 16;

  // read-side swizzle: byte ^= ((row>>2)&1)<<5 ; row&7 == l15&7
  const int rswz = ((l15 >> 2) & 1) << 5;

  auto stageA = [&](int kt, int half) {
    const int bsel = kt & 1, ks = kt % KT_PER_SUB;
    const char* g = gA0 + (size_t)(half * 128) * 768 + ks * 128;
    char* l = smem + LDS_A(bsel) + half * 16384 + lds_off;
    stage16(g, l);
    stage16(g + (size_t)64 * 768, l + 8192);
  };
  auto stageB = [&](int kt, int half) {
    const int bsel = kt & 1, ks = kt % KT_PER_SUB, s = kt / KT_PER_SUB;
    const char* g = gB0 + (size_t)(s * 256 + half * 128) * 768 + ks * 128;
    char* l = smem + LDS_B(bsel) + half * 16384 + lds_off;
    stage16(g, l);
    stage16(g + (size_t)64 * 768, l + 8192);
  };
  auto ldA = [&](int bsel, int m, int kk) -> bf16x8 {
    int byte = (wr * 128 + m * 16 + l15) * 128 + kk * 64 + lhi * 16;
    return load_bf8(smem + LDS_A(bsel) + (byte ^ rswz));
  };
  auto ldB = [&](int bsel, int n, int kk) -> bf16x8 {
    int byte = (wc * 64 + n * 16 + l15) * 128 + kk * 64 + lhi * 16;
    return load_bf8(smem + LDS_B(bsel) + (byte ^ rswz));
  };

  f32x4 acc[8][4];
  f32x4 vm[8];
#pragma unroll
  for (int m = 0; m < 8; ++m) {
    vm[m] = f32x4{-1e30f, -1e30f, -1e30f, -1e30f};
#pragma unroll
    for (int n = 0; n < 4; ++n) acc[m][n] = f32x4{0.f, 0.f, 0.f, 0.f};
  }

  // ---- prologue: tile0 (A0,A1,B0,B1) + tile1 (B0,B1) = 12 loads/thread ----
  stageA(0, 0); stageA(0, 1); stageB(0, 0); stageB(0, 1);
  stageB(1, 0); stageB(1, 1);
  asm volatile("s_waitcnt vmcnt(4)" ::: "memory");
  __builtin_amdgcn_s_barrier();

  bf16x8 bb[4][2];

#define PHASE(BUF, Q, FIRSTKT, STAGE_STMT, VMW) do {                          \
    bf16x8 a00 = ldA(BUF, 2 * (Q), 0),     a01 = ldA(BUF, 2 * (Q), 1);        \
    bf16x8 a10 = ldA(BUF, 2 * (Q) + 1, 0), a11 = ldA(BUF, 2 * (Q) + 1, 1);    \
    if (FIRSTKT) {                                                            \
      _Pragma("unroll")                                                       \
      for (int n = 0; n < 4; ++n) {                                           \
        bb[n][0] = ldB(BUF, n, 0); bb[n][1] = ldB(BUF, n, 1);                 \
      }                                                                       \
    }                                                                         \
    STAGE_STMT;                                                               \
    if (VMW) asm volatile("s_waitcnt vmcnt(4)" ::: "memory");                 \
    __builtin_amdgcn_s_barrier();                                             \
    asm volatile("s_waitcnt lgkmcnt(0)" ::: "memory");                        \
    __builtin_amdgcn_s_setprio(1);                                            \
    _Pragma("unroll")                                                         \
    for (int n = 0; n < 4; ++n) {                                             \
      acc[2*(Q)][n]   = __builtin_amdgcn_mfma_f32_16x16x32_bf16(a00, bb[n][0], acc[2*(Q)][n],   0, 0, 0); \
      acc[2*(Q)][n]   = __builtin_amdgcn_mfma_f32_16x16x32_bf16(a01, bb[n][1], acc[2*(Q)][n],   0, 0, 0); \
      acc[2*(Q)+1][n] = __builtin_amdgcn_mfma_f32_16x16x32_bf16(a10, bb[n][0], acc[2*(Q)+1][n], 0, 0, 0); \
      acc[2*(Q)+1][n] = __builtin_amdgcn_mfma_f32_16x16x32_bf16(a11, bb[n][1], acc[2*(Q)+1][n], 0, 0, 0); \
    }                                                                         \
    __builtin_amdgcn_s_setprio(0);                                            \
    __builtin_amdgcn_s_barrier();                                             \
  } while (0)

  int kt0 = 0;
  for (int it = 0; it < NITER; ++it, kt0 += 2) {
    const int kt1 = kt0 + 1;
    const int n0 = (kt0 + 2) % NKT_TOT;   // even -> buf0
    const int n1 = (kt1 + 2) % NKT_TOT;   // odd  -> buf1
    PHASE(0, 0, true,  stageA(kt1, 0), false);
    PHASE(0, 1, false, stageA(kt1, 1), false);
    PHASE(0, 2, false, stageB(n0, 0),  false);
    PHASE(0, 3, false, stageB(n0, 1),  true);
    PHASE(1, 0, true,  stageA(n0, 0),  false);
    PHASE(1, 1, false, stageA(n0, 1),  false);
    PHASE(1, 2, false, stageB(n1, 0),  false);
    PHASE(1, 3, false, stageB(n1, 1),  true);

    if (it % 3 == 2) {   // subtile boundary: fold acc into running max, reset
#pragma unroll
      for (int m = 0; m < 8; ++m) {
        f32x4 t = acc[m][0];
#pragma unroll
        for (int n = 1; n < 4; ++n)
#pragma unroll
          for (int j = 0; j < 4; ++j) t[j] = fmaxf(t[j], acc[m][n][j]);
#pragma unroll
        for (int j = 0; j < 4; ++j) vm[m][j] = fmaxf(vm[m][j], t[j]);
#pragma unroll
        for (int n = 0; n < 4; ++n) acc[m][n] = f32x4{0.f, 0.f, 0.f, 0.f};
      }
    }
  }
#undef PHASE

  // ---- epilogue: drain, reduce over 16 col-lanes, cross-wave via LDS ----
  asm volatile("s_waitcnt vmcnt(0)" ::: "memory");
#pragma unroll
  for (int d = 1; d < 16; d <<= 1)
#pragma unroll
    for (int m = 0; m < 8; ++m)
#pragma unroll
      for (int j = 0; j < 4; ++j)
        vm[m][j] = fmaxf(vm[m][j], __shfl_xor(vm[m][j], d, 64));

  float* red = (float*)(smem + LDS_RED);
  if (l15 == 0) {
#pragma unroll
    for (int m = 0; m < 8; ++m)
#pragma unroll
      for (int j = 0; j < 4; ++j)
        red[wc * 256 + wr * 128 + m * 16 + lhi * 4 + j] = vm[m][j];
  }
  __syncthreads();
  if (tid < 256) {
    float x = fmaxf(fmaxf(red[tid], red[256 + tid]),
                    fmaxf(red[512 + tid], red[768 + tid]));
    partial[(size_t)grp * NROW_F + brow + tid] = x;
  }
}

// ---------------------------------------------------------------------------
// 3) combine partial maxes -> min_dists = clip(1 - max, 0, 2)
// ---------------------------------------------------------------------------
__global__ __launch_bounds__(256) void combine_kernel(
    const float* __restrict__ partial, float* __restrict__ md) {
  int r = blockIdx.x * 256 + threadIdx.x;
  if (r >= NROW_F) return;
  float m = -1e30f;
#pragma unroll
  for (int c = 0; c < NGRP; ++c) m = fmaxf(m, partial[(size_t)c * NROW_F + r]);
  float d = 1.0f - m;
  d = fminf(fmaxf(d, 0.0f), 2.0f);
  md[r] = d;
}

// ---------------------------------------------------------------------------
// 4) per-batch top-10 mean -> pred_score
// ---------------------------------------------------------------------------
__global__ __launch_bounds__(256) void topk_kernel(
    const float* __restrict__ md, float* __restrict__ out) {
  __shared__ float buf[1024];
  __shared__ float svals[256];
  __shared__ int   sidx[256];
  int b = blockIdx.x, tid = threadIdx.x;
  for (int i = tid; i < 1024; i += 256) buf[i] = md[b * 1024 + i];
  __syncthreads();
  float total = 0.f;
  for (int it = 0; it < 10; ++it) {
    float best = -1e30f; int bi = 0;
    for (int i = tid; i < 1024; i += 256)
      if (buf[i] > best) { best = buf[i]; bi = i; }
    svals[tid] = best; sidx[tid] = bi;
    __syncthreads();
    for (int s = 128; s > 0; s >>= 1) {
      if (tid < s && svals[tid + s] > svals[tid]) {
        svals[tid] = svals[tid + s]; sidx[tid] = sidx[tid + s];
      }
      __syncthreads();
    }
    if (tid == 0) { total += svals[0]; buf[sidx[0]] = -1e30f; }
    __syncthreads();
  }
  if (tid == 0) out[b] = total * 0.1f;
}

// ---------------------------------------------------------------------------
// 5) W = blur_1d ∘ bilinear_resize_1d : 448 x 32 operator.
// ---------------------------------------------------------------------------
__global__ __launch_bounds__(256) void build_w_kernel(float* __restrict__ W) {
  int idx = blockIdx.x * 256 + threadIdx.x;
  if (idx >= 448 * 32) return;
  int y = idx >> 5, g = idx & 31;
  float ksum = 0.f, acc = 0.f;
#pragma unroll
  for (int t = -16; t <= 16; ++t) {
    float ft = (float)t * 0.25f;
    float kv = expf(-0.5f * ft * ft);
    ksum += kv;
    int p = y + t;
    p = (p < 0) ? -p : ((p > 447) ? 894 - p : p);
    float src = ((float)p + 0.5f) * (1.0f / 14.0f) - 0.5f;
    float fl = floorf(src);
    int i0 = (int)fl;
    float fr = src - fl;
    int c0 = i0 < 0 ? 0 : (i0 > 31 ? 31 : i0);
    int i1 = i0 + 1;
    int c1 = i1 < 0 ? 0 : (i1 > 31 ? 31 : i1);
    float w = 0.f;
    if (c0 == g) w += 1.0f - fr;
    if (c1 == g) w += fr;
    acc += kv * w;
  }
  W[idx] = acc / ksum;
}

// ---------------------------------------------------------------------------
// 6) anomaly_map = W · md_grid · W^T
// ---------------------------------------------------------------------------
__global__ __launch_bounds__(256) void map_stage1_kernel(
    const float* __restrict__ md, const float* __restrict__ W,
    float* __restrict__ tmp) {  // 8 x 448 x 32
  int idx = blockIdx.x * 256 + threadIdx.x;
  if (idx >= 8 * 448 * 32) return;
  int gx = idx & 31;
  int y  = (idx >> 5) % 448;
  int b  = idx / (448 * 32);
  const float* w = W + y * 32;
  const float* m = md + b * 1024 + gx;
  float s = 0.f;
#pragma unroll
  for (int gy = 0; gy < 32; ++gy) s += w[gy] * m[gy * 32];
  tmp[idx] = s;
}

__global__ __launch_bounds__(256) void map_stage2_kernel(
    const float* __restrict__ tmp, const float* __restrict__ W,
    float* __restrict__ out) {  // 8 x 448 x 448
  int idx = blockIdx.x * 256 + threadIdx.x;
  if (idx >= 8 * 448 * 448) return;
  int x    = idx % 448;
  int ypos = idx / 448;  // b*448 + y
  const float* w = W + x * 32;
  const float* t = tmp + ypos * 32;
  float s = 0.f;
#pragma unroll
  for (int gx = 0; gx < 32; ++gx) s += w[gx] * t[gx];
  out[idx] = s;
}

// ---------------------------------------------------------------------------
extern "C" void kernel_launch(void* const* d_in, const int* in_sizes, int n_in,
                              void* d_out, int out_size, void* d_ws, size_t ws_size,
                              hipStream_t stream) {
  const float* features = (const float*)d_in[0];   // 8*1024*384
  const float* bank     = (const float*)d_in[1];   // 65536*384
  float* out = (float*)d_out;                      // [8 scores][8*448*448 map]

  char* ws = (char*)d_ws;
  unsigned short* mbh = (unsigned short*)ws;                    // 50,331,648 B
  unsigned short* fh  = (unsigned short*)(ws + 50331648);       //  6,291,456 B
  float* partial      = (float*)(ws + 56623104);                //  1,048,576 B
  float* md           = (float*)(ws + 57671680);                //     32,768 B
  float* W            = (float*)(ws + 57704448);                //     57,344 B
  float* tmp          = (float*)(ws + 57761792);                //    458,752 B

  normalize_rows_kernel<<<NROW_B / 4, 256, 0, stream>>>(bank, mbh, NROW_B);
  normalize_rows_kernel<<<NROW_F / 4, 256, 0, stream>>>(features, fh, NROW_F);
  maxsim_kernel<<<NWG, 512, 0, stream>>>(fh, mbh, partial);
  combine_kernel<<<NROW_F / 256, 256, 0, stream>>>(partial, md);
  topk_kernel<<<8, 256, 0, stream>>>(md, out);
  build_w_kernel<<<(448 * 32 + 255) / 256, 256, 0, stream>>>(W);
  map_stage1_kernel<<<(8 * 448 * 32 + 255) / 256, 256, 0, stream>>>(md, W, tmp);
  map_stage2_kernel<<<(8 * 448 * 448 + 255) / 256, 256, 0, stream>>>(tmp, W, out + 8);
}

// Round 4
// 401.900 us; speedup vs baseline: 6.8294x; 1.0509x over previous
//
#include <hip/hip_runtime.h>
#include <hip/hip_bf16.h>

#define NROW_F 8192
#define NROW_B 65536
#define KDIM   384
#define BM 256
#define BN 256
#define BK 64
#define NSUB 8
#define KT_PER_SUB 6                     // 384/64
#define NKT_TOT (NSUB * KT_PER_SUB)      // 48
#define NITER (NKT_TOT / 2)              // 24
#define NGRP (NROW_B / (BN * NSUB))      // 32
#define NBM  (NROW_F / BM)               // 32
#define NWG  (NBM * NGRP)                // 1024

#define LDS_A(b) ((b) * 32768)
#define LDS_B(b) (65536 + (b) * 32768)
#define LDS_RED  131072
#define LDS_TOTAL 135168

typedef __bf16 bf16x8 __attribute__((ext_vector_type(8)));
typedef short  short8 __attribute__((ext_vector_type(8)));
typedef float  f32x4  __attribute__((ext_vector_type(4)));

static __device__ __forceinline__ unsigned short f2bf(float f) {
  unsigned u = __builtin_bit_cast(unsigned, f);
  u += 0x7FFFu + ((u >> 16) & 1u);
  return (unsigned short)(u >> 16);
}

static __device__ __forceinline__ bf16x8 load_bf8(const void* p) {
  short8 s = *reinterpret_cast<const short8*>(p);
  return __builtin_bit_cast(bf16x8, s);
}

static __device__ __forceinline__ void stage16(const void* g, void* l) {
  __builtin_amdgcn_global_load_lds(
      (const __attribute__((address_space(1))) unsigned int*)g,
      (__attribute__((address_space(3))) unsigned int*)l, 16, 0, 0);
}

// ---------------------------------------------------------------------------
// 1) L2-normalize rows (384 wide), write bf16. One wave per row.
// ---------------------------------------------------------------------------
__global__ __launch_bounds__(256) void normalize_rows_kernel(
    const float* __restrict__ in, unsigned short* __restrict__ out, int nrows) {
  int row  = blockIdx.x * 4 + (threadIdx.x >> 6);
  int lane = threadIdx.x & 63;
  if (row >= nrows) return;
  const float* r = in + (size_t)row * KDIM;
  float v[6];
  float ss = 0.f;
#pragma unroll
  for (int i = 0; i < 6; ++i) { v[i] = r[lane + i * 64]; ss += v[i] * v[i]; }
#pragma unroll
  for (int d = 1; d < 64; d <<= 1) ss += __shfl_xor(ss, d, 64);
  float inv = rsqrtf(fmaxf(ss, 1e-24f));
  unsigned short* o = out + (size_t)row * KDIM;
#pragma unroll
  for (int i = 0; i < 6; ++i) o[lane + i * 64] = f2bf(v[i] * inv);
}

// ---------------------------------------------------------------------------
// 2) maxsim: 256x256 8-phase pipelined MFMA tile (m201 template) with
//    row-max reduction epilogue. 8 waves (2M x 4N), wave out = 128x64.
//    LDS swizzle: chunk(bits 6:4 of row byte) ^= row&7  (conflict-free for
//    128B rows; write side pre-swizzles the GLOBAL source chunk, rule #21).
// ---------------------------------------------------------------------------
__global__ __launch_bounds__(512) void maxsim_kernel(
    const unsigned short* __restrict__ F,   // 8192 x 384 bf16
    const unsigned short* __restrict__ MB,  // 65536 x 384 bf16
    float* __restrict__ partial) {          // NGRP x 8192
  __shared__ __align__(16) char smem[LDS_TOTAL];

  const int tid  = threadIdx.x;
  const int wv   = tid >> 6;
  const int lane = tid & 63;
  const int l15  = lane & 15;
  const int lhi  = lane >> 4;
  const int wr   = wv >> 2;          // 0..1
  const int wc   = wv & 3;           // 0..3

  // XCD-bijective swizzle (NWG % 8 == 0)
  const int wg  = (blockIdx.x & 7) * (NWG / 8) + (blockIdx.x >> 3);
  const int bm  = wg & (NBM - 1);
  const int grp = wg >> 5;
  const size_t brow = (size_t)bm * BM;

  // ---- staging geometry (per lane, constant) ----
  // half-tile = 128 rows x 128 B; issue covers 8 rows x 8 chunks per wave.
  const int srow   = wv * 8 + (lane >> 3);
  const int gchunk = (lane & 7) ^ ((lane >> 3) & 7);   // inverse swizzle
  const int lds_off = wv * 1024;       // + lane*16 added by HW (linear dest)

  const char* gA0 = (const char*)F  + ((size_t)(brow + srow)) * 768 + gchunk * 16;
  const char* gB0 = (const char*)MB + ((size_t)grp * NSUB * 256 + srow) * 768 + gchunk * 16;

  // read-side swizzle: chunk ^= row&7  (row&7 == l15&7 for all fragment rows)
  const int rswz = (l15 & 7) << 4;

  auto stageA = [&](int kt, int half) {
    const int bsel = kt & 1, ks = kt % KT_PER_SUB;
    const char* g = gA0 + (size_t)(half * 128) * 768 + ks * 128;
    char* l = smem + LDS_A(bsel) + half * 16384 + lds_off;
    stage16(g, l);
    stage16(g + (size_t)64 * 768, l + 8192);
  };
  auto stageB = [&](int kt, int half) {
    const int bsel = kt & 1, ks = kt % KT_PER_SUB, s = kt / KT_PER_SUB;
    const char* g = gB0 + (size_t)(s * 256 + half * 128) * 768 + ks * 128;
    char* l = smem + LDS_B(bsel) + half * 16384 + lds_off;
    stage16(g, l);
    stage16(g + (size_t)64 * 768, l + 8192);
  };
  auto ldA = [&](int bsel, int m, int kk) -> bf16x8 {
    int byte = (wr * 128 + m * 16 + l15) * 128 + kk * 64 + lhi * 16;
    return load_bf8(smem + LDS_A(bsel) + (byte ^ rswz));
  };
  auto ldB = [&](int bsel, int n, int kk) -> bf16x8 {
    int byte = (wc * 64 + n * 16 + l15) * 128 + kk * 64 + lhi * 16;
    return load_bf8(smem + LDS_B(bsel) + (byte ^ rswz));
  };

  f32x4 acc[8][4];
  f32x4 vm[8];
#pragma unroll
  for (int m = 0; m < 8; ++m) {
    vm[m] = f32x4{-1e30f, -1e30f, -1e30f, -1e30f};
#pragma unroll
    for (int n = 0; n < 4; ++n) acc[m][n] = f32x4{0.f, 0.f, 0.f, 0.f};
  }

  // ---- prologue: tile0 (A0,A1,B0,B1) + tile1 (B0,B1) = 12 loads/thread ----
  stageA(0, 0); stageA(0, 1); stageB(0, 0); stageB(0, 1);
  stageB(1, 0); stageB(1, 1);
  asm volatile("s_waitcnt vmcnt(4)" ::: "memory");
  __builtin_amdgcn_s_barrier();

  bf16x8 bb[4][2];

#define PHASE(BUF, Q, FIRSTKT, STAGE_STMT, VMW) do {                          \
    bf16x8 a00 = ldA(BUF, 2 * (Q), 0),     a01 = ldA(BUF, 2 * (Q), 1);        \
    bf16x8 a10 = ldA(BUF, 2 * (Q) + 1, 0), a11 = ldA(BUF, 2 * (Q) + 1, 1);    \
    if (FIRSTKT) {                                                            \
      _Pragma("unroll")                                                       \
      for (int n = 0; n < 4; ++n) {                                           \
        bb[n][0] = ldB(BUF, n, 0); bb[n][1] = ldB(BUF, n, 1);                 \
      }                                                                       \
    }                                                                         \
    STAGE_STMT;                                                               \
    if (VMW) asm volatile("s_waitcnt vmcnt(4)" ::: "memory");                 \
    __builtin_amdgcn_s_barrier();                                             \
    asm volatile("s_waitcnt lgkmcnt(0)" ::: "memory");                        \
    __builtin_amdgcn_s_setprio(1);                                            \
    _Pragma("unroll")                                                         \
    for (int n = 0; n < 4; ++n) {                                             \
      acc[2*(Q)][n]   = __builtin_amdgcn_mfma_f32_16x16x32_bf16(a00, bb[n][0], acc[2*(Q)][n],   0, 0, 0); \
      acc[2*(Q)][n]   = __builtin_amdgcn_mfma_f32_16x16x32_bf16(a01, bb[n][1], acc[2*(Q)][n],   0, 0, 0); \
      acc[2*(Q)+1][n] = __builtin_amdgcn_mfma_f32_16x16x32_bf16(a10, bb[n][0], acc[2*(Q)+1][n], 0, 0, 0); \
      acc[2*(Q)+1][n] = __builtin_amdgcn_mfma_f32_16x16x32_bf16(a11, bb[n][1], acc[2*(Q)+1][n], 0, 0, 0); \
    }                                                                         \
    __builtin_amdgcn_s_setprio(0);                                            \
    __builtin_amdgcn_s_barrier();                                             \
  } while (0)

  int kt0 = 0;
  for (int it = 0; it < NITER; ++it, kt0 += 2) {
    const int kt1 = kt0 + 1;
    const int n0 = (kt0 + 2) % NKT_TOT;   // even -> buf0
    const int n1 = (kt1 + 2) % NKT_TOT;   // odd  -> buf1
    PHASE(0, 0, true,  stageA(kt1, 0), false);
    PHASE(0, 1, false, stageA(kt1, 1), false);
    PHASE(0, 2, false, stageB(n0, 0),  false);
    PHASE(0, 3, false, stageB(n0, 1),  true);
    PHASE(1, 0, true,  stageA(n0, 0),  false);
    PHASE(1, 1, false, stageA(n0, 1),  false);
    PHASE(1, 2, false, stageB(n1, 0),  false);
    PHASE(1, 3, false, stageB(n1, 1),  true);

    if (it % 3 == 2) {   // subtile boundary: fold acc into running max, reset
#pragma unroll
      for (int m = 0; m < 8; ++m) {
        f32x4 t = acc[m][0];
#pragma unroll
        for (int n = 1; n < 4; ++n)
#pragma unroll
          for (int j = 0; j < 4; ++j) t[j] = fmaxf(t[j], acc[m][n][j]);
#pragma unroll
        for (int j = 0; j < 4; ++j) vm[m][j] = fmaxf(vm[m][j], t[j]);
#pragma unroll
        for (int n = 0; n < 4; ++n) acc[m][n] = f32x4{0.f, 0.f, 0.f, 0.f};
      }
    }
  }
#undef PHASE

  // ---- epilogue: drain, reduce over 16 col-lanes, cross-wave via LDS ----
  asm volatile("s_waitcnt vmcnt(0)" ::: "memory");
#pragma unroll
  for (int d = 1; d < 16; d <<= 1)
#pragma unroll
    for (int m = 0; m < 8; ++m)
#pragma unroll
      for (int j = 0; j < 4; ++j)
        vm[m][j] = fmaxf(vm[m][j], __shfl_xor(vm[m][j], d, 64));

  float* red = (float*)(smem + LDS_RED);
  if (l15 == 0) {
#pragma unroll
    for (int m = 0; m < 8; ++m)
#pragma unroll
      for (int j = 0; j < 4; ++j)
        red[wc * 256 + wr * 128 + m * 16 + lhi * 4 + j] = vm[m][j];
  }
  __syncthreads();
  if (tid < 256) {
    float x = fmaxf(fmaxf(red[tid], red[256 + tid]),
                    fmaxf(red[512 + tid], red[768 + tid]));
    partial[(size_t)grp * NROW_F + brow + tid] = x;
  }
}

// ---------------------------------------------------------------------------
// 3) combine partial maxes -> min_dists = clip(1 - max, 0, 2)
// ---------------------------------------------------------------------------
__global__ __launch_bounds__(256) void combine_kernel(
    const float* __restrict__ partial, float* __restrict__ md) {
  int r = blockIdx.x * 256 + threadIdx.x;
  if (r >= NROW_F) return;
  float m = -1e30f;
#pragma unroll
  for (int c = 0; c < NGRP; ++c) m = fmaxf(m, partial[(size_t)c * NROW_F + r]);
  float d = 1.0f - m;
  d = fminf(fmaxf(d, 0.0f), 2.0f);
  md[r] = d;
}

// ---------------------------------------------------------------------------
// 4) per-batch top-10 mean -> pred_score
// ---------------------------------------------------------------------------
__global__ __launch_bounds__(256) void topk_kernel(
    const float* __restrict__ md, float* __restrict__ out) {
  __shared__ float buf[1024];
  __shared__ float svals[256];
  __shared__ int   sidx[256];
  int b = blockIdx.x, tid = threadIdx.x;
  for (int i = tid; i < 1024; i += 256) buf[i] = md[b * 1024 + i];
  __syncthreads();
  float total = 0.f;
  for (int it = 0; it < 10; ++it) {
    float best = -1e30f; int bi = 0;
    for (int i = tid; i < 1024; i += 256)
      if (buf[i] > best) { best = buf[i]; bi = i; }
    svals[tid] = best; sidx[tid] = bi;
    __syncthreads();
    for (int s = 128; s > 0; s >>= 1) {
      if (tid < s && svals[tid + s] > svals[tid]) {
        svals[tid] = svals[tid + s]; sidx[tid] = sidx[tid + s];
      }
      __syncthreads();
    }
    if (tid == 0) { total += svals[0]; buf[sidx[0]] = -1e30f; }
    __syncthreads();
  }
  if (tid == 0) out[b] = total * 0.1f;
}

// ---------------------------------------------------------------------------
// 5) W = blur_1d ∘ bilinear_resize_1d : 448 x 32 operator.
// ---------------------------------------------------------------------------
__global__ __launch_bounds__(256) void build_w_kernel(float* __restrict__ W) {
  int idx = blockIdx.x * 256 + threadIdx.x;
  if (idx >= 448 * 32) return;
  int y = idx >> 5, g = idx & 31;
  float ksum = 0.f, acc = 0.f;
#pragma unroll
  for (int t = -16; t <= 16; ++t) {
    float ft = (float)t * 0.25f;
    float kv = expf(-0.5f * ft * ft);
    ksum += kv;
    int p = y + t;
    p = (p < 0) ? -p : ((p > 447) ? 894 - p : p);
    float src = ((float)p + 0.5f) * (1.0f / 14.0f) - 0.5f;
    float fl = floorf(src);
    int i0 = (int)fl;
    float fr = src - fl;
    int c0 = i0 < 0 ? 0 : (i0 > 31 ? 31 : i0);
    int i1 = i0 + 1;
    int c1 = i1 < 0 ? 0 : (i1 > 31 ? 31 : i1);
    float w = 0.f;
    if (c0 == g) w += 1.0f - fr;
    if (c1 == g) w += fr;
    acc += kv * w;
  }
  W[idx] = acc / ksum;
}

// ---------------------------------------------------------------------------
// 6) anomaly_map = W · md_grid · W^T
// ---------------------------------------------------------------------------
__global__ __launch_bounds__(256) void map_stage1_kernel(
    const float* __restrict__ md, const float* __restrict__ W,
    float* __restrict__ tmp) {  // 8 x 448 x 32
  int idx = blockIdx.x * 256 + threadIdx.x;
  if (idx >= 8 * 448 * 32) return;
  int gx = idx & 31;
  int y  = (idx >> 5) % 448;
  int b  = idx / (448 * 32);
  const float* w = W + y * 32;
  const float* m = md + b * 1024 + gx;
  float s = 0.f;
#pragma unroll
  for (int gy = 0; gy < 32; ++gy) s += w[gy] * m[gy * 32];
  tmp[idx] = s;
}

__global__ __launch_bounds__(256) void map_stage2_kernel(
    const float* __restrict__ tmp, const float* __restrict__ W,
    float* __restrict__ out) {  // 8 x 448 x 448
  int idx = blockIdx.x * 256 + threadIdx.x;
  if (idx >= 8 * 448 * 448) return;
  int x    = idx % 448;
  int ypos = idx / 448;  // b*448 + y
  const float* w = W + x * 32;
  const float* t = tmp + ypos * 32;
  float s = 0.f;
#pragma unroll
  for (int gx = 0; gx < 32; ++gx) s += w[gx] * t[gx];
  out[idx] = s;
}

// ---------------------------------------------------------------------------
extern "C" void kernel_launch(void* const* d_in, const int* in_sizes, int n_in,
                              void* d_out, int out_size, void* d_ws, size_t ws_size,
                              hipStream_t stream) {
  const float* features = (const float*)d_in[0];   // 8*1024*384
  const float* bank     = (const float*)d_in[1];   // 65536*384
  float* out = (float*)d_out;                      // [8 scores][8*448*448 map]

  char* ws = (char*)d_ws;
  unsigned short* mbh = (unsigned short*)ws;                    // 50,331,648 B
  unsigned short* fh  = (unsigned short*)(ws + 50331648);       //  6,291,456 B
  float* partial      = (float*)(ws + 56623104);                //  1,048,576 B
  float* md           = (float*)(ws + 57671680);                //     32,768 B
  float* W            = (float*)(ws + 57704448);                //     57,344 B
  float* tmp          = (float*)(ws + 57761792);                //    458,752 B

  normalize_rows_kernel<<<NROW_B / 4, 256, 0, stream>>>(bank, mbh, NROW_B);
  normalize_rows_kernel<<<NROW_F / 4, 256, 0, stream>>>(features, fh, NROW_F);
  maxsim_kernel<<<NWG, 512, 0, stream>>>(fh, mbh, partial);
  combine_kernel<<<NROW_F / 256, 256, 0, stream>>>(partial, md);
  topk_kernel<<<8, 256, 0, stream>>>(md, out);
  build_w_kernel<<<(448 * 32 + 255) / 256, 256, 0, stream>>>(W);
  map_stage1_kernel<<<(8 * 448 * 32 + 255) / 256, 256, 0, stream>>>(md, W, tmp);
  map_stage2_kernel<<<(8 * 448 * 448 + 255) / 256, 256, 0, stream>>>(tmp, W, out + 8);
}

// Round 7
// 259.161 us; speedup vs baseline: 10.5909x; 1.5508x over previous
//
#include <hip/hip_runtime.h>
#include <hip/hip_bf16.h>

#define NROW_F 8192
#define NROW_B 65536
#define KDIM   384
#define BM 256
#define BN 256
#define NSUB 8
#define NGRP (NROW_B / (BN * NSUB))      // 32
#define NBM  (NROW_F / BM)               // 32
#define NWG  (NBM * NGRP)                // 1024

// LDS map (bytes): A 6 K-tiles resident, B triple-buffered, sB slice, red aliases B
#define LDSA 0                 // 6 * 16384 = 98304
#define LDSB 98304             // 3 * 16384 = 49152
#define LDSS 147456            // 8192 (2048 f32 sB slice)
#define LDSR 98304             // epilogue red[4][256] aliases B bufs
#define LDS_TOT 155648

typedef int   i32x4 __attribute__((ext_vector_type(4)));
typedef float f32x4 __attribute__((ext_vector_type(4)));

static __device__ __forceinline__ void stage16(const void* g, void* l) {
  __builtin_amdgcn_global_load_lds(
      (const __attribute__((address_space(1))) unsigned int*)g,
      (__attribute__((address_space(3))) unsigned int*)l, 16, 0, 0);
}

// ---------------------------------------------------------------------------
// 1) L2-normalize rows + symmetric i8 quantization with per-row scale.
//    q = rint(127 * x / maxabs(x)); scale = maxabs * inv_norm / 127.
// ---------------------------------------------------------------------------
__global__ __launch_bounds__(256) void quantize_rows_kernel(
    const float* __restrict__ in, char* __restrict__ out8,
    float* __restrict__ scales, int nrows) {
  int row  = blockIdx.x * 4 + (threadIdx.x >> 6);
  int lane = threadIdx.x & 63;
  if (row >= nrows) return;
  const float* r = in + (size_t)row * KDIM;
  float v[6];
  float ss = 0.f, mx = 0.f;
#pragma unroll
  for (int i = 0; i < 6; ++i) {
    v[i] = r[lane + i * 64];
    ss += v[i] * v[i];
    mx = fmaxf(mx, fabsf(v[i]));
  }
#pragma unroll
  for (int d = 1; d < 64; d <<= 1) {
    ss += __shfl_xor(ss, d, 64);
    mx = fmaxf(mx, __shfl_xor(mx, d, 64));
  }
  mx = fmaxf(mx, 1e-30f);
  float inv = rsqrtf(fmaxf(ss, 1e-24f));
  float scl = 127.0f / mx;
  if (lane == 0) scales[row] = mx * inv * (1.0f / 127.0f);
  char* o = out8 + (size_t)row * KDIM;
#pragma unroll
  for (int i = 0; i < 6; ++i)
    o[lane + i * 64] = (char)__float2int_rn(v[i] * scl);
}

// ---------------------------------------------------------------------------
// 2) maxsim: i8 MFMA 16x16x64, A fully LDS-resident (6 K-tiles), B triple-
//    buffered with counted vmcnt(4). 8 waves (2M x 4N), wave out = 128x64.
//    NOTE: global_load_lds global address is PER-LANE (LDS dest is uniform
//    base + lane*16) — every stage16 source must include the lane term.
//    Round-6 bug: sB slice staged from a wave-uniform address -> LDS held 64
//    copies of 4 floats -> wrong per-col scales (deterministic 3.1e-2 error).
// ---------------------------------------------------------------------------
__global__ __launch_bounds__(512) void maxsim_kernel(
    const char* __restrict__ F8,    // 8192 x 384 i8
    const char* __restrict__ B8,    // 65536 x 384 i8
    const float* __restrict__ sA,   // 8192
    const float* __restrict__ sB,   // 65536
    float* __restrict__ partial) {  // NGRP x 8192 (max sim)
  __shared__ __align__(16) char smem[LDS_TOT];

  const int tid  = threadIdx.x;
  const int wv   = tid >> 6;
  const int lane = tid & 63;
  const int l15  = lane & 15;
  const int lhi  = lane >> 4;
  const int wr   = wv >> 2;          // 0..1
  const int wc   = wv & 3;           // 0..3

  // XCD-bijective swizzle (NWG % 8 == 0); co-resident blocks share grp.
  const int wg  = (blockIdx.x & 7) * (NWG / 8) + (blockIdx.x >> 3);
  const int bm  = wg & (NBM - 1);
  const int grp = wg >> 5;
  const size_t brow = (size_t)bm * BM;

  // ---- staging geometry: 16KB tile = 256 rows x 64B; wave = 32 rows ----
  const int srow16 = lane >> 2;                        // row within 16-row grp
  const int gsw    = (lane & 3) ^ ((lane >> 3) & 3);   // inverse write swizzle

  // A prologue: 6 K-tiles staged once (12 issues/thread)
  {
    const char* gA = F8 + ((size_t)(brow + wv * 32 + srow16)) * KDIM + gsw * 16;
    char* lA = smem + LDSA + wv * 2048;
#pragma unroll
    for (int kt = 0; kt < 6; ++kt) {
      stage16(gA + kt * 64,              lA + kt * 16384);
      stage16(gA + kt * 64 + 16 * KDIM,  lA + kt * 16384 + 1024);
    }
  }
  // sB slice (2048 floats = 8KB): PER-LANE source (+ lane*16), uniform dest.
  stage16((const char*)(sB + (size_t)grp * 2048) + wv * 1024 + lane * 16,
          smem + LDSS + wv * 1024);

  auto stageB = [&](int kt, int buf) {
    const char* g = B8 + ((size_t)grp * 2048 + (kt / 6) * 256 + wv * 32 + srow16) * KDIM
                    + (kt % 6) * 64 + gsw * 16;
    char* l = smem + LDSB + buf * 16384 + wv * 2048;
    stage16(g, l);
    stage16(g + 16 * KDIM, l + 1024);
  };
  stageB(0, 0);
  stageB(1, 1);

  // read-side swizzle: chunk(lhi) ^= (row>>1)&3, row ≡ l15 (bases mult of 16)
  const int cof = ((l15 >> 1) & 3) << 4;

  auto ldA8 = [&](int k6, int m) -> i32x4 {
    int byte = k6 * 16384 + (wr * 128 + m * 16 + l15) * 64 + ((lhi << 4) ^ cof);
    return *reinterpret_cast<const i32x4*>(smem + LDSA + byte);
  };
  auto ldB8 = [&](int buf, int n) -> i32x4 {
    int byte = buf * 16384 + (wc * 64 + n * 16 + l15) * 64 + ((lhi << 4) ^ cof);
    return *reinterpret_cast<const i32x4*>(smem + LDSB + byte);
  };

  i32x4 acc[8][4];
  f32x4 vm[8];
#pragma unroll
  for (int m = 0; m < 8; ++m) {
    vm[m] = f32x4{-1e30f, -1e30f, -1e30f, -1e30f};
#pragma unroll
    for (int n = 0; n < 4; ++n) acc[m][n] = i32x4{0, 0, 0, 0};
  }

  for (int sub = 0; sub < NSUB; ++sub) {
#pragma unroll
    for (int k6 = 0; k6 < 6; ++k6) {
      const int kt = sub * 6 + k6;
      // ALWAYS stage (wrap at the tail) so vmcnt(4) waits for B(kt).
      stageB((kt + 2) % (NSUB * 6), (k6 + 2) % 3);
      asm volatile("s_waitcnt vmcnt(4)" ::: "memory");
      __builtin_amdgcn_s_barrier();

      i32x4 a[8], b[4];
#pragma unroll
      for (int m = 0; m < 8; ++m) a[m] = ldA8(k6, m);
#pragma unroll
      for (int n = 0; n < 4; ++n) b[n] = ldB8(k6 % 3, n);
      asm volatile("s_waitcnt lgkmcnt(0)" ::: "memory");
      __builtin_amdgcn_s_setprio(1);
#pragma unroll
      for (int n = 0; n < 4; ++n)
#pragma unroll
        for (int m = 0; m < 8; ++m)
          acc[m][n] = __builtin_amdgcn_mfma_i32_16x16x64_i8(a[m], b[n], acc[m][n], 0, 0, 0);
      __builtin_amdgcn_s_setprio(0);
      asm volatile("" ::: "memory");   // keep reads above the barrier
      __builtin_amdgcn_s_barrier();
    }
    // fold subtile: vm = max(vm, acc * sB[col]); reset acc
    float sb[4];
#pragma unroll
    for (int n = 0; n < 4; ++n)
      sb[n] = *reinterpret_cast<const float*>(
          smem + LDSS + (sub * 256 + wc * 64 + n * 16 + l15) * 4);
#pragma unroll
    for (int m = 0; m < 8; ++m) {
#pragma unroll
      for (int n = 0; n < 4; ++n)
#pragma unroll
        for (int j = 0; j < 4; ++j)
          vm[m][j] = fmaxf(vm[m][j], (float)acc[m][n][j] * sb[n]);
#pragma unroll
      for (int n = 0; n < 4; ++n) acc[m][n] = i32x4{0, 0, 0, 0};
    }
  }

  // ---- epilogue ----
  asm volatile("s_waitcnt vmcnt(0)" ::: "memory");
#pragma unroll
  for (int d = 1; d < 16; d <<= 1)
#pragma unroll
    for (int m = 0; m < 8; ++m)
#pragma unroll
      for (int j = 0; j < 4; ++j)
        vm[m][j] = fmaxf(vm[m][j], __shfl_xor(vm[m][j], d, 64));

  float* red = (float*)(smem + LDSR);
  __syncthreads();
  if (l15 == 0) {
#pragma unroll
    for (int m = 0; m < 8; ++m)
#pragma unroll
      for (int j = 0; j < 4; ++j)
        red[wc * 256 + wr * 128 + m * 16 + lhi * 4 + j] = vm[m][j];
  }
  __syncthreads();
  if (tid < 256) {
    float x = fmaxf(fmaxf(red[tid], red[256 + tid]),
                    fmaxf(red[512 + tid], red[768 + tid]));
    partial[(size_t)grp * NROW_F + brow + tid] = x * sA[brow + tid];
  }
}

// ---------------------------------------------------------------------------
// 3) combine partial maxes -> min_dists = clip(1 - max, 0, 2)
// ---------------------------------------------------------------------------
__global__ __launch_bounds__(256) void combine_kernel(
    const float* __restrict__ partial, float* __restrict__ md) {
  int r = blockIdx.x * 256 + threadIdx.x;
  if (r >= NROW_F) return;
  float m = -1e30f;
#pragma unroll
  for (int c = 0; c < NGRP; ++c) m = fmaxf(m, partial[(size_t)c * NROW_F + r]);
  float d = 1.0f - m;
  d = fminf(fmaxf(d, 0.0f), 2.0f);
  md[r] = d;
}

// ---------------------------------------------------------------------------
// 4) per-batch top-10 mean -> pred_score
// ---------------------------------------------------------------------------
__global__ __launch_bounds__(256) void topk_kernel(
    const float* __restrict__ md, float* __restrict__ out) {
  __shared__ float buf[1024];
  __shared__ float svals[256];
  __shared__ int   sidx[256];
  int b = blockIdx.x, tid = threadIdx.x;
  for (int i = tid; i < 1024; i += 256) buf[i] = md[b * 1024 + i];
  __syncthreads();
  float total = 0.f;
  for (int it = 0; it < 10; ++it) {
    float best = -1e30f; int bi = 0;
    for (int i = tid; i < 1024; i += 256)
      if (buf[i] > best) { best = buf[i]; bi = i; }
    svals[tid] = best; sidx[tid] = bi;
    __syncthreads();
    for (int s = 128; s > 0; s >>= 1) {
      if (tid < s && svals[tid + s] > svals[tid]) {
        svals[tid] = svals[tid + s]; sidx[tid] = sidx[tid + s];
      }
      __syncthreads();
    }
    if (tid == 0) { total += svals[0]; buf[sidx[0]] = -1e30f; }
    __syncthreads();
  }
  if (tid == 0) out[b] = total * 0.1f;
}

// ---------------------------------------------------------------------------
// 5) W = blur_1d ∘ bilinear_resize_1d : 448 x 32 operator.
// ---------------------------------------------------------------------------
__global__ __launch_bounds__(256) void build_w_kernel(float* __restrict__ W) {
  int idx = blockIdx.x * 256 + threadIdx.x;
  if (idx >= 448 * 32) return;
  int y = idx >> 5, g = idx & 31;
  float ksum = 0.f, acc = 0.f;
#pragma unroll
  for (int t = -16; t <= 16; ++t) {
    float ft = (float)t * 0.25f;
    float kv = expf(-0.5f * ft * ft);
    ksum += kv;
    int p = y + t;
    p = (p < 0) ? -p : ((p > 447) ? 894 - p : p);
    float src = ((float)p + 0.5f) * (1.0f / 14.0f) - 0.5f;
    float fl = floorf(src);
    int i0 = (int)fl;
    float fr = src - fl;
    int c0 = i0 < 0 ? 0 : (i0 > 31 ? 31 : i0);
    int i1 = i0 + 1;
    int c1 = i1 < 0 ? 0 : (i1 > 31 ? 31 : i1);
    float w = 0.f;
    if (c0 == g) w += 1.0f - fr;
    if (c1 == g) w += fr;
    acc += kv * w;
  }
  W[idx] = acc / ksum;
}

// ---------------------------------------------------------------------------
// 6) anomaly_map = W · md_grid · W^T
// ---------------------------------------------------------------------------
__global__ __launch_bounds__(256) void map_stage1_kernel(
    const float* __restrict__ md, const float* __restrict__ W,
    float* __restrict__ tmp) {  // 8 x 448 x 32
  int idx = blockIdx.x * 256 + threadIdx.x;
  if (idx >= 8 * 448 * 32) return;
  int gx = idx & 31;
  int y  = (idx >> 5) % 448;
  int b  = idx / (448 * 32);
  const float* w = W + y * 32;
  const float* m = md + b * 1024 + gx;
  float s = 0.f;
#pragma unroll
  for (int gy = 0; gy < 32; ++gy) s += w[gy] * m[gy * 32];
  tmp[idx] = s;
}

__global__ __launch_bounds__(256) void map_stage2_kernel(
    const float* __restrict__ tmp, const float* __restrict__ W,
    float* __restrict__ out) {  // 8 x 448 x 448
  int idx = blockIdx.x * 256 + threadIdx.x;
  if (idx >= 8 * 448 * 448) return;
  int x    = idx % 448;
  int ypos = idx / 448;  // b*448 + y
  const float* w = W + x * 32;
  const float* t = tmp + ypos * 32;
  float s = 0.f;
#pragma unroll
  for (int gx = 0; gx < 32; ++gx) s += w[gx] * t[gx];
  out[idx] = s;
}

// ---------------------------------------------------------------------------
extern "C" void kernel_launch(void* const* d_in, const int* in_sizes, int n_in,
                              void* d_out, int out_size, void* d_ws, size_t ws_size,
                              hipStream_t stream) {
  const float* features = (const float*)d_in[0];   // 8*1024*384
  const float* bank     = (const float*)d_in[1];   // 65536*384
  float* out = (float*)d_out;                      // [8 scores][8*448*448 map]

  char* ws = (char*)d_ws;
  char*  mb8     = ws;                              // 25,165,824 B
  char*  f8      = ws + 25165824;                   //  3,145,728 B
  float* sB      = (float*)(ws + 28311552);         //    262,144 B
  float* sA      = (float*)(ws + 28573696);         //     32,768 B
  float* partial = (float*)(ws + 28606464);         //  1,048,576 B
  float* md      = (float*)(ws + 29655040);         //     32,768 B
  float* W       = (float*)(ws + 29687808);         //     57,344 B
  float* tmp     = (float*)(ws + 29745152);         //    458,752 B

  quantize_rows_kernel<<<NROW_B / 4, 256, 0, stream>>>(bank, mb8, sB, NROW_B);
  quantize_rows_kernel<<<NROW_F / 4, 256, 0, stream>>>(features, f8, sA, NROW_F);
  maxsim_kernel<<<NWG, 512, 0, stream>>>(f8, mb8, sA, sB, partial);
  combine_kernel<<<NROW_F / 256, 256, 0, stream>>>(partial, md);
  topk_kernel<<<8, 256, 0, stream>>>(md, out);
  build_w_kernel<<<(448 * 32 + 255) / 256, 256, 0, stream>>>(W);
  map_stage1_kernel<<<(8 * 448 * 32 + 255) / 256, 256, 0, stream>>>(md, W, tmp);
  map_stage2_kernel<<<(8 * 448 * 448 + 255) / 256, 256, 0, stream>>>(tmp, W, out + 8);
}